// Round 1
// baseline (14257.906 us; speedup 1.0000x reference)
//
#include <hip/hip_runtime.h>
#include <stdint.h>

#define Bsz 4096
#define Tn  128
#define Hn  128      // ENC = DEC = 128
#define NTH 512

typedef float f4v __attribute__((ext_vector_type(4)));

__device__ __forceinline__ float rcp_f(float x) { return __builtin_amdgcn_rcpf(x); }

// tanh(x) = 1 - 2/(e^{2x}+1); saturates correctly at +/-inf (rcp(inf)=0)
__device__ __forceinline__ float tanh_f(float x) {
    float p = __expf(2.0f * x);
    return 1.0f - 2.0f * rcp_f(p + 1.0f);
}
__device__ __forceinline__ float sig_f(float x) {
    return rcp_f(1.0f + __expf(-x));
}
// pack two fp32 -> bf16 pair (round-to-nearest-even), a in low 16, b in high 16
__device__ __forceinline__ uint32_t pack_bf2(float a, float b) {
    union { float f; uint32_t u; } ua, ub;
    ua.f = a; ub.f = b;
    uint32_t x = ua.u + (0x7fffu + ((ua.u >> 16) & 1u));
    uint32_t y = ub.u + (0x7fffu + ((ub.u >> 16) & 1u));
    return (x >> 16) | (y & 0xffff0000u);
}
__device__ __forceinline__ float bf_lo(uint32_t p) {
    union { uint32_t u; float f; } v; v.u = p << 16; return v.f;
}
__device__ __forceinline__ float bf_hi(uint32_t p) {
    union { uint32_t u; float f; } v; v.u = p & 0xffff0000u; return v.f;
}

__global__ __launch_bounds__(NTH, 2)
void dec_kernel(const float* __restrict__ X,    // (B,T,128)
                const float* __restrict__ yh,   // (B,127,1)
                const float* __restrict__ W1,   // (128,384): [:, :128]=W1h, [:,128:256]=W1c, [:,256:]=W1e
                const float* __restrict__ b1,   // (128)
                const float* __restrict__ W2,   // (1,128)
                const float* __restrict__ b2,   // (1)
                const float* __restrict__ Wih,  // (512,1)
                const float* __restrict__ Whh,  // (512,128)
                const float* __restrict__ bih,  // (512)
                const float* __restrict__ bhh,  // (512)
                const float* __restrict__ fcW,  // (1,129)
                const float* __restrict__ fcb,  // (1)
                const float* __restrict__ Wff,  // (1,256)
                const float* __restrict__ bff,  // (1)
                float* __restrict__ out)        // (B,1)
{
    const int b    = blockIdx.x;
    const int tid  = threadIdx.x;
    const int lane = tid & 63;
    const int wv   = tid >> 6;

    // strides chosen so hot scalar reads are bank-conflict-free:
    //  Xs stride 132: bank=(4t+e)%32 -> 2-way over 64 lanes (free)
    //  EP stride 129: bank=(t+h)%32  -> 2-way over 64 lanes (free)
    __shared__ __align__(16) float Xs[Tn][132];
    __shared__ __align__(16) float EP[Tn][129];
    __shared__ __align__(16) float h_s[Hn];
    __shared__ __align__(16) float c_s[Hn];
    __shared__ __align__(16) float hc_s[Hn];
    __shared__ __align__(16) float ctx_s[Hn];
    __shared__ __align__(16) float e_part[4][Tn];
    __shared__ __align__(16) float beta_s[Tn];
    __shared__ __align__(16) float ctx_part[4][Hn];
    __shared__ __align__(16) float g_s[4 * Hn];
    __shared__ __align__(16) float y_s[Tn];
    __shared__ float red_s[4];

    const float* Xb = X + (size_t)b * (Tn * Hn);

    // ---- stage X[b] into LDS (coalesced float4) ----
    #pragma unroll
    for (int u = 0; u < 8; ++u) {
        int f4i = tid + NTH * u;          // 0..4095 float4s
        int t   = f4i >> 5;               // 32 float4 per row
        int c4  = f4i & 31;
        f4v v = ((const f4v*)Xb)[f4i];
        *(f4v*)&Xs[t][c4 * 4] = v;
    }
    if (tid < Hn)     { h_s[tid] = 0.f; c_s[tid] = 0.f; ctx_s[tid] = 0.f; }
    if (tid < Tn - 1) { y_s[tid] = yh[(size_t)b * (Tn - 1) + tid]; }
    __syncthreads();

    const int jA = tid >> 2;   // 0..127
    const int qA = tid & 3;    // k-chunk of 32

    // ---- enc_proj: EP[t][j] = sum_e Xs[t][e] * W1e[j][e] (fp32 VALU, one-time) ----
    {
        float w1e[32];
        #pragma unroll
        for (int u4 = 0; u4 < 8; ++u4) {
            f4v w = *(const f4v*)(W1 + jA * 384 + 256 + 32 * qA + 4 * u4);
            #pragma unroll
            for (int k = 0; k < 4; ++k) w1e[4 * u4 + k] = w[k];
        }
        for (int t = 0; t < Tn; ++t) {
            float acc = 0.f;
            const f4v* xp = (const f4v*)&Xs[t][32 * qA];
            #pragma unroll
            for (int u4 = 0; u4 < 8; ++u4) {
                f4v xv = xp[u4];
                acc += xv[0] * w1e[4 * u4 + 0] + xv[1] * w1e[4 * u4 + 1]
                     + xv[2] * w1e[4 * u4 + 2] + xv[3] * w1e[4 * u4 + 3];
            }
            acc += __shfl_xor(acc, 1);
            acc += __shfl_xor(acc, 2);
            if (qA == 0) EP[t][jA] = acc;
        }
    }

    // ---- persistent register weights ----
    float w1h[32], w1c[32];
    #pragma unroll
    for (int u4 = 0; u4 < 8; ++u4) {
        f4v a = *(const f4v*)(W1 + jA * 384 + 32 * qA + 4 * u4);
        f4v c = *(const f4v*)(W1 + jA * 384 + 128 + 32 * qA + 4 * u4);
        #pragma unroll
        for (int k = 0; k < 4; ++k) { w1h[4 * u4 + k] = a[k]; w1c[4 * u4 + k] = c[k]; }
    }
    const int tB = tid & 127;  // t (phase B) / e (phase C)
    const int qB = tid >> 7;   // chunk index 0..3
    float w2s[32];
    #pragma unroll
    for (int u4 = 0; u4 < 8; ++u4) {
        f4v w = *(const f4v*)(W2 + 32 * qB + 4 * u4);
        #pragma unroll
        for (int k = 0; k < 4; ++k) w2s[4 * u4 + k] = w[k];
    }
    uint32_t whh[64];  // W_hh row `tid`, bf16-packed pairs
    #pragma unroll
    for (int u4 = 0; u4 < 32; ++u4) {
        f4v w = *(const f4v*)(Whh + (size_t)tid * 128 + 4 * u4);
        whh[2 * u4]     = pack_bf2(w[0], w[1]);
        whh[2 * u4 + 1] = pack_bf2(w[2], w[3]);
    }
    float wihv = Wih[tid];
    float bgv  = bih[tid] + bhh[tid];
    float b1j  = b1[jA];
    float b2v  = b2[0];
    float fcbv = fcb[0];
    float fcwy = fcW[128];
    float fw0 = 0.f, fw1 = 0.f, wh0 = 0.f, wh1 = 0.f, wc0 = 0.f, wc1 = 0.f;
    if (tid < 64) {
        fw0 = fcW[lane];       fw1 = fcW[lane + 64];
        wh0 = Wff[lane];       wh1 = Wff[lane + 64];
        wc0 = Wff[128 + lane]; wc1 = Wff[192 + lane];
    }
    __syncthreads();

    // ================= scan: 127 steps =================
    for (int s = 0; s < Tn - 1; ++s) {
        // -- A: hc_proj[j] = b1[j] + h.W1h[j,:] + c.W1c[j,:]
        {
            float acc = 0.f;
            const f4v* h4 = (const f4v*)&h_s[32 * qA];
            const f4v* c4 = (const f4v*)&c_s[32 * qA];
            #pragma unroll
            for (int u4 = 0; u4 < 8; ++u4) {
                f4v hv = h4[u4], cv = c4[u4];
                acc += hv[0] * w1h[4 * u4 + 0] + hv[1] * w1h[4 * u4 + 1]
                     + hv[2] * w1h[4 * u4 + 2] + hv[3] * w1h[4 * u4 + 3];
                acc += cv[0] * w1c[4 * u4 + 0] + cv[1] * w1c[4 * u4 + 1]
                     + cv[2] * w1c[4 * u4 + 2] + cv[3] * w1c[4 * u4 + 3];
            }
            acc += __shfl_xor(acc, 1);
            acc += __shfl_xor(acc, 2);
            if (qA == 0) hc_s[jA] = acc + b1j;
        }
        __syncthreads();

        // -- B: logit partials: e[t] += sum_{h in chunk} w2[h]*tanh(EP[t][h]+hc[h])
        {
            float acc = 0.f;
            #pragma unroll
            for (int u = 0; u < 32; ++u) {
                int hh = 32 * qB + u;
                float sum = EP[tB][hh] + hc_s[hh];
                acc += w2s[u] * tanh_f(sum);
            }
            e_part[qB][tB] = acc;
        }
        __syncthreads();

        // -- softmax over t (wave 0 only; 2 logits/lane)
        if (wv == 0) {
            float v0 = e_part[0][lane] + e_part[1][lane] + e_part[2][lane] + e_part[3][lane] + b2v;
            float v1 = e_part[0][lane + 64] + e_part[1][lane + 64]
                     + e_part[2][lane + 64] + e_part[3][lane + 64] + b2v;
            float m = fmaxf(v0, v1);
            #pragma unroll
            for (int d = 1; d < 64; d <<= 1) m = fmaxf(m, __shfl_xor(m, d));
            float p0 = __expf(v0 - m), p1 = __expf(v1 - m);
            float ssum = p0 + p1;
            #pragma unroll
            for (int d = 1; d < 64; d <<= 1) ssum += __shfl_xor(ssum, d);
            float inv = rcp_f(ssum);
            beta_s[lane]      = p0 * inv;
            beta_s[lane + 64] = p1 * inv;
        }
        __syncthreads();

        // -- C: context partials: ctx[e] += sum_{t in chunk} beta[t]*Xs[t][e]
        {
            float acc = 0.f;
            #pragma unroll
            for (int u = 0; u < 32; ++u) {
                int t = 32 * qB + u;
                acc += beta_s[t] * Xs[t][tB];
            }
            ctx_part[qB][tB] = acc;
        }
        __syncthreads();

        // -- ctx reduce + y_tilde partial (wave 0)
        if (wv == 0) {
            float c0 = ctx_part[0][lane] + ctx_part[1][lane] + ctx_part[2][lane] + ctx_part[3][lane];
            float c1 = ctx_part[0][lane + 64] + ctx_part[1][lane + 64]
                     + ctx_part[2][lane + 64] + ctx_part[3][lane + 64];
            ctx_s[lane]      = c0;
            ctx_s[lane + 64] = c1;
            float yv = c0 * fw0 + c1 * fw1;
            #pragma unroll
            for (int d = 1; d < 64; d <<= 1) yv += __shfl_xor(yv, d);
            if (lane == 0) red_s[0] = yv;
        }
        __syncthreads();

        // -- D: gates[j] = bias + Wih[j]*y_tilde + h.Whh[j,:]
        {
            float yt = y_s[s];
            float ytilde = red_s[0] + fcwy * yt + fcbv;
            float acc = bgv + wihv * ytilde;
            const f4v* h4 = (const f4v*)h_s;
            #pragma unroll
            for (int u4 = 0; u4 < 32; ++u4) {
                f4v hv = h4[u4];
                uint32_t p0 = whh[2 * u4], p1 = whh[2 * u4 + 1];
                acc += hv[0] * bf_lo(p0) + hv[1] * bf_hi(p0)
                     + hv[2] * bf_lo(p1) + hv[3] * bf_hi(p1);
            }
            g_s[tid] = acc;
        }
        __syncthreads();

        // -- E: LSTM pointwise update
        if (tid < Hn) {
            float gi = g_s[tid], gf = g_s[128 + tid], gg = g_s[256 + tid], go = g_s[384 + tid];
            float cn = sig_f(gf) * c_s[tid] + sig_f(gi) * tanh_f(gg);
            float hn = sig_f(go) * tanh_f(cn);
            c_s[tid] = cn;
            h_s[tid] = hn;
        }
        __syncthreads();
    }

    // ---- final: out[b] = [h, ctx] . Wff + bff ----
    if (wv == 0) {
        float v = h_s[lane] * wh0 + h_s[lane + 64] * wh1
                + ctx_s[lane] * wc0 + ctx_s[lane + 64] * wc1;
        #pragma unroll
        for (int d = 1; d < 64; d <<= 1) v += __shfl_xor(v, d);
        if (lane == 0) out[b] = v + bff[0];
    }
}

extern "C" void kernel_launch(void* const* d_in, const int* in_sizes, int n_in,
                              void* d_out, int out_size, void* d_ws, size_t ws_size,
                              hipStream_t stream) {
    dec_kernel<<<Bsz, NTH, 0, stream>>>(
        (const float*)d_in[0],  (const float*)d_in[1],  (const float*)d_in[2],
        (const float*)d_in[3],  (const float*)d_in[4],  (const float*)d_in[5],
        (const float*)d_in[6],  (const float*)d_in[7],  (const float*)d_in[8],
        (const float*)d_in[9],  (const float*)d_in[10], (const float*)d_in[11],
        (const float*)d_in[12], (const float*)d_in[13], (float*)d_out);
}